// Round 1
// 273.225 us; speedup vs baseline: 1.0067x; 1.0067x over previous
//
#include <hip/hip_runtime.h>
#include <hip/hip_bf16.h>
#include <hip/hip_fp16.h>

#define N_NODES   100000
#define N_EDGES   1600000
#define N_GRAPHS  1024
#define EMB       32
#define HID       64
#define N_CLASSES 10
#define SCAN_BLOCKS 391   // ceil(100000/256)
#define NCOMBO 153        // 17 shape ids x 9 color ids
#define BUCK_NODES 448    // nodes per dst-bucket
#define NBUCK 224         // ceil(100000/448)
#define BIN_CAP 8192      // per-bucket staging capacity (mean 7143, +12 sigma)
#define EPB 4096          // edges per binA block

// ---------------- prep: combo[v], per-graph counts ----------------
__global__ __launch_bounds__(256) void prep_kernel(
    const int* __restrict__ sid, const int* __restrict__ cid,
    const int* __restrict__ batch, int* __restrict__ combo, int* __restrict__ cnt) {
    int v = blockIdx.x * 256 + threadIdx.x;
    if (v < N_NODES) {
        combo[v] = sid[v] * 9 + cid[v];
        atomicAdd(&cnt[batch[v]], 1);
    }
}

// ---------------- combined table (fp16): TCh[s*9+c][j] = (st[s]@W1)[j] + (ct[c]@W1)[j] ----------------
__global__ __launch_bounds__(64) void tc_kernel(
    const float* __restrict__ st, const float* __restrict__ ct,
    const float* __restrict__ W1, __half* __restrict__ TCh) {
    int r = blockIdx.x, j = threadIdx.x;
    int s = r / 9, c = r % 9;
    float acc = 0.0f;
    if (s != 0) {
#pragma unroll
        for (int k = 0; k < EMB; ++k) acc = fmaf(st[s * EMB + k], W1[k * HID + j], acc);
    }
    if (c != 0) {
#pragma unroll
        for (int k = 0; k < EMB; ++k) acc = fmaf(ct[c * EMB + k], W1[k * HID + j], acc);
    }
    TCh[r * HID + j] = __float2half_rn(acc);
}

// ---------------- binA: block-local counting sort by dst-bucket, chunked flush ----------------
__global__ __launch_bounds__(512) void binA_kernel(
    const int* __restrict__ src, const int* __restrict__ dst,
    const int* __restrict__ combo, int* __restrict__ gcur,
    int2* __restrict__ gbin) {
    __shared__ int2 stg[EPB];            // 32 KB
    __shared__ int hist[NBUCK];
    __shared__ int base[NBUCK + 1];
    __shared__ int gstart[NBUCK];
    __shared__ int scanbuf[256];
    int t = threadIdx.x;
    int e0 = blockIdx.x * EPB;
    for (int i = t; i < NBUCK; i += 512) hist[i] = 0;
    __syncthreads();

    int2 myq[8];
    int mybo[8];
#pragma unroll
    for (int i = 0; i < 8; ++i) {
        int e = e0 + t + i * 512;
        if (e < N_EDGES) {
            int d = dst[e];
            int s = src[e];
            unsigned b = (unsigned)d / BUCK_NODES;
            int off = atomicAdd(&hist[b], 1);
            myq[i].x = s | (combo[s] << 17);
            myq[i].y = d;
            mybo[i] = (int)(b << 16) | off;
        } else {
            mybo[i] = -1;
        }
    }
    __syncthreads();

    int h = (t < NBUCK) ? hist[t] : 0;
    if (t < 256) scanbuf[t] = h;
    __syncthreads();
#pragma unroll
    for (int off = 1; off < 256; off <<= 1) {
        int x = (t < 256 && t >= off) ? scanbuf[t - off] : 0;
        __syncthreads();
        if (t < 256) scanbuf[t] += x;
        __syncthreads();
    }
    if (t < NBUCK) base[t] = scanbuf[t] - h;
    if (t == 0) base[NBUCK] = scanbuf[255];
    __syncthreads();
#pragma unroll
    for (int i = 0; i < 8; ++i) {
        if (mybo[i] >= 0) {
            int b = mybo[i] >> 16, off = mybo[i] & 0xFFFF;
            stg[base[b] + off] = myq[i];
        }
    }
    if (t < NBUCK) {
        int n = hist[t];
        gstart[t] = n ? atomicAdd(&gcur[t], n) : 0;
    }
    __syncthreads();
    int total = base[NBUCK];
    for (int i = t; i < total; i += 512) {
        int2 q = stg[i];
        unsigned b = (unsigned)q.y / BUCK_NODES;
        gbin[(size_t)b * BIN_CAP + gstart[b] + (i - base[b])] = q;
    }
}

// ---------------- bscan: exclusive scan of gcur[224] -> bktbase ----------------
__global__ __launch_bounds__(256) void bscan_kernel(const int* __restrict__ gcur,
                                                    int* __restrict__ bktbase) {
    __shared__ int s[256];
    int t = threadIdx.x;
    int g = (t < NBUCK) ? gcur[t] : 0;
    s[t] = g; __syncthreads();
#pragma unroll
    for (int off = 1; off < 256; off <<= 1) {
        int x = (t >= off) ? s[t - off] : 0;
        __syncthreads();
        s[t] += x;
        __syncthreads();
    }
    if (t < NBUCK) bktbase[t] = s[t] - g;
}

// ---------------- bucket: per-bucket degrees -> dis + rowptr ----------------
__global__ __launch_bounds__(512) void bucket_kernel(
    const int2* __restrict__ gbin, const int* __restrict__ gcur,
    const int* __restrict__ bktbase, float* __restrict__ dis,
    int* __restrict__ rowptr) {
    __shared__ int ldeg[BUCK_NODES];
    __shared__ int s[512];
    int b = blockIdx.x, t = threadIdx.x;
    for (int i = t; i < BUCK_NODES; i += 512) ldeg[i] = 0;
    __syncthreads();
    int n = gcur[b];
    const int2* mybin = gbin + (size_t)b * BIN_CAP;
    for (int i = t; i < n; i += 512)
        atomicAdd(&ldeg[mybin[i].y - b * BUCK_NODES], 1);
    __syncthreads();
    int d = (t < BUCK_NODES) ? ldeg[t] : 0;
    int v = b * BUCK_NODES + t;
    if (t < BUCK_NODES && v < N_NODES) dis[v] = rsqrtf(1.0f + (float)d);
    s[t] = d;
    __syncthreads();
#pragma unroll
    for (int off = 1; off < 512; off <<= 1) {
        int x = (t >= off) ? s[t - off] : 0;
        __syncthreads();
        s[t] += x;
        __syncthreads();
    }
    if (t < BUCK_NODES && v < N_NODES) rowptr[v] = bktbase[b] + s[t] - d;
    if (b == 0 && t == 0) rowptr[N_NODES] = N_EDGES;
}

// ---------------- binB: per-bucket fine scatter to CSR (1024 threads) ----------------
// epack.x = (src << 15) | (combo*128)   [src: 17b, combo byte-offset: 15b]
// epack.y = dis[src] as float bits
__global__ __launch_bounds__(1024) void binB_kernel(
    const int2* __restrict__ gbin, const int* __restrict__ gcur,
    const int* __restrict__ rowptr, const float* __restrict__ dis,
    int2* __restrict__ epack) {
    __shared__ int curs[BUCK_NODES];
    int b = blockIdx.x, t = threadIdx.x;
    for (int i = t; i < BUCK_NODES; i += 1024) curs[i] = 0;
    __syncthreads();
    int n = gcur[b];
    const int2* mybin = gbin + (size_t)b * BIN_CAP;
    for (int i = t; i < n; i += 1024) {
        int2 q = mybin[i];
        int local = q.y - b * BUCK_NODES;
        int r = atomicAdd(&curs[local], 1);
        unsigned sx = (unsigned)q.x;
        int srci = (int)(sx & 0x1FFFF);
        int comboOff = (int)((sx >> 17) * 128u);   // <= 19456, fits 15 bits
        int2 rec;
        rec.x = (srci << 15) | comboOff;
        rec.y = __float_as_int(dis[srci]);
        epack[rowptr[q.y] + r] = rec;
    }
}

// ---------------- per-node edge accumulate for layer 1 ----------------
// q: lane i holds edge record rs+i (clamped).  All loads coalesced; broadcast
// per edge via v_readlane (VALU, no SMEM OOO-lgkmcnt serialization).
__device__ __forceinline__ float agg1_node(const int2* __restrict__ epack, int2 q,
                                           int rs, int re, int lane, int lane2,
                                           const __half* TCs) {
    float acc = 0.0f;
    int p = rs;
    for (;;) {
        int avail = re - p;
        int cnt = avail > 64 ? 64 : avail;
        int vx = q.x & 0x7FFF;   // combo byte-offset, vectorized unpack (1 op / 64 edges)
        int vw = q.y;
        int j = 0;
        for (; j + 8 <= cnt; j += 8) {
            float tv[8], sw[8];
#pragma unroll
            for (int i = 0; i < 8; ++i) {
                int off = __builtin_amdgcn_readlane(vx, j + i);
                sw[i] = __int_as_float(__builtin_amdgcn_readlane(vw, j + i));
                tv[i] = __half2float(*(const __half*)((const char*)TCs + (off + lane2)));
            }
#pragma unroll
            for (int i = 0; i < 8; ++i) acc = fmaf(sw[i], tv[i], acc);
        }
        if (j < cnt) {   // masked tail chunk (data from clamped lanes is real/finite)
#pragma unroll
            for (int i = 0; i < 8; ++i) {
                int jj = j + i;
                int off = __builtin_amdgcn_readlane(vx, jj & 63);
                float w_ = __int_as_float(__builtin_amdgcn_readlane(vw, jj & 63));
                float tv = __half2float(*(const __half*)((const char*)TCs + (off + lane2)));
                acc = fmaf(jj < cnt ? w_ : 0.0f, tv, acc);
            }
        }
        p += 64;
        if (p >= re) break;                 // common case: single pass (deg <= 64)
        int idx = p + lane;
        idx = idx < N_EDGES ? idx : N_EDGES - 1;
        q = epack[idx];
    }
    return acc;
}

// ---------------- fused layer-1 aggregate + mm2: 4 nodes/wave, coalesced edge staging ----------------
__global__ __launch_bounds__(256, 4) void agg1_mm2_kernel(
    const int2* __restrict__ epack, const int* __restrict__ rowptr,
    const int* __restrict__ combo, const float* __restrict__ dis,
    const __half* __restrict__ TCh, const float* __restrict__ W2,
    const float* __restrict__ b1, __half* __restrict__ h2s) {
    __shared__ __align__(16) __half TCs[NCOMBO * HID];  // 19,584 B
    __shared__ __align__(16) float xs[4][HID];          //  1,024 B
    int t = threadIdx.x;
    {
        const int4* s4 = (const int4*)TCh;
        int4* d4 = (int4*)TCs;
        for (int i = t; i < NCOMBO * HID * 2 / 16; i += 256) d4[i] = s4[i];
    }
    __syncthreads();
    int lane = t & 63, w = t >> 6;
    int lane2 = lane * 2;
    int v0 = (blockIdx.x * 4 + w) * 4;

    // scalar row pointers
    int r0 = __builtin_amdgcn_readfirstlane(rowptr[v0]);
    int r1 = __builtin_amdgcn_readfirstlane(rowptr[v0 + 1]);
    int r2 = __builtin_amdgcn_readfirstlane(rowptr[v0 + 2]);
    int r3 = __builtin_amdgcn_readfirstlane(rowptr[v0 + 3]);
    int r4 = __builtin_amdgcn_readfirstlane(rowptr[v0 + 4]);

    // prefetch all 4 nodes' edge buffers (one coalesced load each, vmcnt-counted)
    int ia = r0 + lane; ia = ia < N_EDGES ? ia : N_EDGES - 1;
    int ib = r1 + lane; ib = ib < N_EDGES ? ib : N_EDGES - 1;
    int ic = r2 + lane; ic = ic < N_EDGES ? ic : N_EDGES - 1;
    int id = r3 + lane; id = id < N_EDGES ? id : N_EDGES - 1;
    int2 qa = epack[ia];
    int2 qb = epack[ib];
    int2 qc = epack[ic];
    int2 qd = epack[id];

    float bias = b1[lane];
    float wcol[HID];   // W2 column pinned in VGPRs (launch_bounds caps at 128)
#pragma unroll
    for (int k = 0; k < HID; ++k) wcol[k] = W2[k * HID + lane];

#define AGG1_EPILOGUE(V, ACC)                                                  \
    {                                                                          \
        float dv = dis[V];                                                     \
        float hv = __half2float(TCs[combo[V] * HID + lane]);                   \
        float val = dv * fmaf(hv, dv, ACC) + bias;                             \
        val = val > 0.0f ? val : 0.0f;                                         \
        xs[w][lane] = val;                                                     \
        float acc2 = 0.0f;                                                     \
        _Pragma("unroll")                                                      \
        for (int k4 = 0; k4 < HID / 4; ++k4) {                                 \
            float4 xv = *(const float4*)(&xs[w][k4 * 4]);                      \
            acc2 = fmaf(xv.x, wcol[k4 * 4 + 0], acc2);                         \
            acc2 = fmaf(xv.y, wcol[k4 * 4 + 1], acc2);                         \
            acc2 = fmaf(xv.z, wcol[k4 * 4 + 2], acc2);                         \
            acc2 = fmaf(xv.w, wcol[k4 * 4 + 3], acc2);                         \
        }                                                                      \
        h2s[(size_t)(V) * HID + lane] = __float2half_rn(acc2 * dv);            \
    }

    {
        float acc = agg1_node(epack, qa, r0, r1, lane, lane2, TCs);
        AGG1_EPILOGUE(v0, acc)
    }
    {
        float acc = agg1_node(epack, qb, r1, r2, lane, lane2, TCs);
        AGG1_EPILOGUE(v0 + 1, acc)
    }
    {
        float acc = agg1_node(epack, qc, r2, r3, lane, lane2, TCs);
        AGG1_EPILOGUE(v0 + 2, acc)
    }
    {
        float acc = agg1_node(epack, qd, r3, r4, lane, lane2, TCs);
        AGG1_EPILOGUE(v0 + 3, acc)
    }
#undef AGG1_EPILOGUE
}

// ---------------- per-node edge accumulate for layer 2 ----------------
// sx: lane i holds epack[rs+i].x.  Broadcast h2s byte-offset per edge via readlane;
// gathers are per-lane vector loads (vmcnt, 8-deep in flight).
__device__ __forceinline__ float agg2_node(const int* __restrict__ epackx, int sx,
                                           int rs, int re, int lane, int lane2,
                                           const __half* __restrict__ h2s) {
    float acc = 0.0f;
    int p = rs;
    for (;;) {
        int avail = re - p;
        int cnt = avail > 64 ? 64 : avail;
        int vo = (int)((((unsigned)sx) >> 15) << 7);   // src*128, vectorized unpack
        int j = 0;
        for (; j + 8 <= cnt; j += 8) {
            float g[8];
#pragma unroll
            for (int i = 0; i < 8; ++i) {
                int off = __builtin_amdgcn_readlane(vo, j + i);
                g[i] = __half2float(*(const __half*)((const char*)h2s + (off + lane2)));
            }
#pragma unroll
            for (int i = 0; i < 8; ++i) acc += g[i];
        }
        if (j < cnt) {
#pragma unroll
            for (int i = 0; i < 8; ++i) {
                int jj = j + i;
                int off = __builtin_amdgcn_readlane(vo, jj & 63);
                float gv = __half2float(*(const __half*)((const char*)h2s + (off + lane2)));
                acc += (jj < cnt) ? gv : 0.0f;
            }
        }
        p += 64;
        if (p >= re) break;
        int idx = p + lane;
        idx = idx < N_EDGES ? idx : N_EDGES - 1;
        sx = epackx[idx * 2];
    }
    return acc;
}

// ---------------- layer-2 aggregate + pool: 4 nodes/wave, run-merged atomics ----------------
__global__ __launch_bounds__(256, 8) void agg2_pool_kernel(
    const int2* __restrict__ epack, const int* __restrict__ rowptr,
    const __half* __restrict__ h2s, const float* __restrict__ dis,
    const float* __restrict__ b2, const int* __restrict__ batch,
    float* __restrict__ pooled) {
    int t = threadIdx.x, lane = t & 63, w = t >> 6;
    int lane2 = lane * 2;
    const int* epackx = (const int*)epack;
    int v0 = (blockIdx.x * 4 + w) * 4;   // grid 6250

    int r0 = __builtin_amdgcn_readfirstlane(rowptr[v0]);
    int r1 = __builtin_amdgcn_readfirstlane(rowptr[v0 + 1]);
    int r2 = __builtin_amdgcn_readfirstlane(rowptr[v0 + 2]);
    int r3 = __builtin_amdgcn_readfirstlane(rowptr[v0 + 3]);
    int r4 = __builtin_amdgcn_readfirstlane(rowptr[v0 + 4]);

    int ia = r0 + lane; ia = ia < N_EDGES ? ia : N_EDGES - 1;
    int ib = r1 + lane; ib = ib < N_EDGES ? ib : N_EDGES - 1;
    int ic = r2 + lane; ic = ic < N_EDGES ? ic : N_EDGES - 1;
    int id = r3 + lane; id = id < N_EDGES ? id : N_EDGES - 1;
    int sa = epackx[ia * 2];
    int sb = epackx[ib * 2];
    int sc = epackx[ic * 2];
    int sd = epackx[id * 2];

    float bv = b2[lane];
    float acc0 = agg2_node(epackx, sa, r0, r1, lane, lane2, h2s);
    float acc1 = agg2_node(epackx, sb, r1, r2, lane, lane2, h2s);
    float acc2 = agg2_node(epackx, sc, r2, r3, lane, lane2, h2s);
    float acc3 = agg2_node(epackx, sd, r3, r4, lane, lane2, h2s);

#define AGG2_VAL(V, ACC, OUT)                                                  \
    {                                                                          \
        float dv = dis[V];                                                     \
        float self = __half2float(h2s[(size_t)(V) * HID + lane]);              \
        float val = dv * ((ACC) + self) + bv;                                  \
        OUT = val > 0.0f ? val : 0.0f;                                         \
    }
    float val0, val1, val2, val3;
    AGG2_VAL(v0, acc0, val0)
    AGG2_VAL(v0 + 1, acc1, val1)
    AGG2_VAL(v0 + 2, acc2, val2)
    AGG2_VAL(v0 + 3, acc3, val3)
#undef AGG2_VAL

    int g0 = __builtin_amdgcn_readfirstlane(batch[v0]);
    int g1 = __builtin_amdgcn_readfirstlane(batch[v0 + 1]);
    int g2 = __builtin_amdgcn_readfirstlane(batch[v0 + 2]);
    int g3 = __builtin_amdgcn_readfirstlane(batch[v0 + 3]);
    // batch is sorted: merge same-graph contributions into one atomic per run
    float s = val0; int g = g0;
    if (g1 == g) { s += val1; } else { unsafeAtomicAdd(&pooled[g * HID + lane], s); g = g1; s = val1; }
    if (g2 == g) { s += val2; } else { unsafeAtomicAdd(&pooled[g * HID + lane], s); g = g2; s = val2; }
    if (g3 == g) { s += val3; } else { unsafeAtomicAdd(&pooled[g * HID + lane], s); g = g3; s = val3; }
    unsafeAtomicAdd(&pooled[g * HID + lane], s);
}

// ---------------- logits ----------------
__global__ __launch_bounds__(64) void logits_kernel(
    const float* __restrict__ pooled, const int* __restrict__ cnt,
    const float* __restrict__ Wl, const float* __restrict__ bl,
    float* __restrict__ out) {
    __shared__ float row[HID];
    int g = blockIdx.x, t = threadIdx.x;
    int c = cnt[g]; if (c < 1) c = 1;
    row[t] = pooled[g * HID + t] / (float)c;
    __syncthreads();
    if (t < N_CLASSES) {
        float acc = bl[t];
#pragma unroll
        for (int k = 0; k < HID; ++k) acc = fmaf(row[k], Wl[k * N_CLASSES + t], acc);
        out[g * N_CLASSES + t] = acc;
    }
}

extern "C" void kernel_launch(void* const* d_in, const int* in_sizes, int n_in,
                              void* d_out, int out_size, void* d_ws, size_t ws_size,
                              hipStream_t stream) {
    const int*   shape_id = (const int*)d_in[0];
    const int*   color_id = (const int*)d_in[1];
    const int*   edge_idx = (const int*)d_in[2];
    const int*   batch    = (const int*)d_in[3];
    const float* st       = (const float*)d_in[4];
    const float* ct       = (const float*)d_in[5];
    const float* W1       = (const float*)d_in[6];
    const float* b1       = (const float*)d_in[7];
    const float* W2       = (const float*)d_in[8];
    const float* b2       = (const float*)d_in[9];
    const float* Wl       = (const float*)d_in[10];
    const float* bl       = (const float*)d_in[11];
    float* out = (float*)d_out;

    const int* src = edge_idx;
    const int* dst = edge_idx + N_EDGES;

    // workspace layout
    char* ws = (char*)d_ws;
    int*    combo   = (int*)   (ws + 0);            //   400,384 B
    float*  dis     = (float*) (ws + 400384);       //   400,384 B
    int*    bktbase = (int*)   (ws + 800768);       //     1,024 B
    int*    rowptr  = (int*)   (ws + 1201152);      //   400,384 B
    __half* TCh     = (__half*)(ws + 1603584);      //    19,968 B
    float*  pooled  = (float*) (ws + 1623552);      //   262,144 B
    int*    cnt     = (int*)   (ws + 1885696);      //     4,096 B
    int*    gcur    = (int*)   (ws + 1889792);      //     1,024 B
    int2*   epack   = (int2*)  (ws + 1890816);      // 12,800,000 B
    int2*   gbin    = (int2*)  (ws + 14690816);     // 14,680,064 B
    __half* h2s     = (__half*)(ws + 29370880);     // 12,800,000 B (total ~42.2 MB)

    hipMemsetAsync(pooled, 0, N_GRAPHS * HID * sizeof(float) + N_GRAPHS * sizeof(int), stream);
    hipMemsetAsync(gcur, 0, NBUCK * sizeof(int), stream);

    // 1. per-node combo + per-graph counts
    prep_kernel<<<SCAN_BLOCKS, 256, 0, stream>>>(shape_id, color_id, batch, combo, cnt);

    // 2. combined (shape,color)->h1 table (fp16)
    tc_kernel<<<NCOMBO, 64, 0, stream>>>(st, ct, W1, TCh);

    // 3. bin edges by dst-bucket
    binA_kernel<<<(N_EDGES + EPB - 1) / EPB, 512, 0, stream>>>(src, dst, combo, gcur, gbin);

    // 4. bucket bases from gcur
    bscan_kernel<<<1, 256, 0, stream>>>(gcur, bktbase);

    // 5. per-bucket degrees -> dis + rowptr
    bucket_kernel<<<NBUCK, 512, 0, stream>>>(gbin, gcur, bktbase, dis, rowptr);

    // 6. per-bucket scatter to CSR (1024 thr), new epack packing
    binB_kernel<<<NBUCK, 1024, 0, stream>>>(gbin, gcur, rowptr, dis, epack);

    // 7. fused layer-1 aggregate + mm2 -> h2s (4 nodes/wave, readlane broadcast)
    agg1_mm2_kernel<<<6250, 256, 0, stream>>>(epack, rowptr, combo, dis, TCh, W2, b1, h2s);

    // 8. layer-2 aggregate + pool (4 nodes/wave, run-merged atomics)
    agg2_pool_kernel<<<6250, 256, 0, stream>>>(epack, rowptr, h2s, dis, b2, batch, pooled);

    // 9. logits
    logits_kernel<<<N_GRAPHS, 64, 0, stream>>>(pooled, cnt, Wl, bl, out);
}

// Round 2
// 243.918 us; speedup vs baseline: 1.1276x; 1.1202x over previous
//
#include <hip/hip_runtime.h>
#include <hip/hip_bf16.h>
#include <hip/hip_fp16.h>

#define N_NODES   100000
#define N_EDGES   1600000
#define N_GRAPHS  1024
#define EMB       32
#define HID       64
#define N_CLASSES 10
#define SCAN_BLOCKS 391   // ceil(100000/256)
#define NCOMBO 153        // 17 shape ids x 9 color ids
#define BUCK_NODES 448    // nodes per dst-bucket
#define NBUCK 224         // ceil(100000/448)
#define BIN_CAP 8192      // per-bucket staging capacity (mean 7143, +12 sigma)
#define EPB 4096          // edges per binA block

typedef _Float16 f16x8 __attribute__((ext_vector_type(8)));
typedef float f32x4 __attribute__((ext_vector_type(4)));

// ---------------- prep: combo[v], per-graph counts ----------------
__global__ __launch_bounds__(256) void prep_kernel(
    const int* __restrict__ sid, const int* __restrict__ cid,
    const int* __restrict__ batch, int* __restrict__ combo, int* __restrict__ cnt) {
    int v = blockIdx.x * 256 + threadIdx.x;
    if (v < N_NODES) {
        combo[v] = sid[v] * 9 + cid[v];
        atomicAdd(&cnt[batch[v]], 1);
    }
}

// ---------------- combined table (fp16): TCh[s*9+c][j] = (st[s]@W1)[j] + (ct[c]@W1)[j] ----------------
__global__ __launch_bounds__(64) void tc_kernel(
    const float* __restrict__ st, const float* __restrict__ ct,
    const float* __restrict__ W1, __half* __restrict__ TCh) {
    int r = blockIdx.x, j = threadIdx.x;
    int s = r / 9, c = r % 9;
    float acc = 0.0f;
    if (s != 0) {
#pragma unroll
        for (int k = 0; k < EMB; ++k) acc = fmaf(st[s * EMB + k], W1[k * HID + j], acc);
    }
    if (c != 0) {
#pragma unroll
        for (int k = 0; k < EMB; ++k) acc = fmaf(ct[c * EMB + k], W1[k * HID + j], acc);
    }
    TCh[r * HID + j] = __float2half_rn(acc);
}

// ---------------- binA: block-local counting sort by dst-bucket, chunked flush ----------------
__global__ __launch_bounds__(512) void binA_kernel(
    const int* __restrict__ src, const int* __restrict__ dst,
    const int* __restrict__ combo, int* __restrict__ gcur,
    int2* __restrict__ gbin) {
    __shared__ int2 stg[EPB];            // 32 KB
    __shared__ int hist[NBUCK];
    __shared__ int base[NBUCK + 1];
    __shared__ int gstart[NBUCK];
    __shared__ int scanbuf[256];
    int t = threadIdx.x;
    int e0 = blockIdx.x * EPB;
    for (int i = t; i < NBUCK; i += 512) hist[i] = 0;
    __syncthreads();

    int2 myq[8];
    int mybo[8];
#pragma unroll
    for (int i = 0; i < 8; ++i) {
        int e = e0 + t + i * 512;
        if (e < N_EDGES) {
            int d = dst[e];
            int s = src[e];
            unsigned b = (unsigned)d / BUCK_NODES;
            int off = atomicAdd(&hist[b], 1);
            myq[i].x = s | (combo[s] << 17);
            myq[i].y = d;
            mybo[i] = (int)(b << 16) | off;
        } else {
            mybo[i] = -1;
        }
    }
    __syncthreads();

    int h = (t < NBUCK) ? hist[t] : 0;
    if (t < 256) scanbuf[t] = h;
    __syncthreads();
#pragma unroll
    for (int off = 1; off < 256; off <<= 1) {
        int x = (t < 256 && t >= off) ? scanbuf[t - off] : 0;
        __syncthreads();
        if (t < 256) scanbuf[t] += x;
        __syncthreads();
    }
    if (t < NBUCK) base[t] = scanbuf[t] - h;
    if (t == 0) base[NBUCK] = scanbuf[255];
    __syncthreads();
#pragma unroll
    for (int i = 0; i < 8; ++i) {
        if (mybo[i] >= 0) {
            int b = mybo[i] >> 16, off = mybo[i] & 0xFFFF;
            stg[base[b] + off] = myq[i];
        }
    }
    if (t < NBUCK) {
        int n = hist[t];
        gstart[t] = n ? atomicAdd(&gcur[t], n) : 0;
    }
    __syncthreads();
    int total = base[NBUCK];
    for (int i = t; i < total; i += 512) {
        int2 q = stg[i];
        unsigned b = (unsigned)q.y / BUCK_NODES;
        gbin[(size_t)b * BIN_CAP + gstart[b] + (i - base[b])] = q;
    }
}

// ---------------- bscan: exclusive scan of gcur[224] -> bktbase ----------------
__global__ __launch_bounds__(256) void bscan_kernel(const int* __restrict__ gcur,
                                                    int* __restrict__ bktbase) {
    __shared__ int s[256];
    int t = threadIdx.x;
    int g = (t < NBUCK) ? gcur[t] : 0;
    s[t] = g; __syncthreads();
#pragma unroll
    for (int off = 1; off < 256; off <<= 1) {
        int x = (t >= off) ? s[t - off] : 0;
        __syncthreads();
        s[t] += x;
        __syncthreads();
    }
    if (t < NBUCK) bktbase[t] = s[t] - g;
}

// ---------------- bucket: per-bucket degrees -> dis + rowptr ----------------
__global__ __launch_bounds__(512) void bucket_kernel(
    const int2* __restrict__ gbin, const int* __restrict__ gcur,
    const int* __restrict__ bktbase, float* __restrict__ dis,
    int* __restrict__ rowptr) {
    __shared__ int ldeg[BUCK_NODES];
    __shared__ int s[512];
    int b = blockIdx.x, t = threadIdx.x;
    for (int i = t; i < BUCK_NODES; i += 512) ldeg[i] = 0;
    __syncthreads();
    int n = gcur[b];
    const int2* mybin = gbin + (size_t)b * BIN_CAP;
    for (int i = t; i < n; i += 512)
        atomicAdd(&ldeg[mybin[i].y - b * BUCK_NODES], 1);
    __syncthreads();
    int d = (t < BUCK_NODES) ? ldeg[t] : 0;
    int v = b * BUCK_NODES + t;
    if (t < BUCK_NODES && v < N_NODES) dis[v] = rsqrtf(1.0f + (float)d);
    s[t] = d;
    __syncthreads();
#pragma unroll
    for (int off = 1; off < 512; off <<= 1) {
        int x = (t >= off) ? s[t - off] : 0;
        __syncthreads();
        s[t] += x;
        __syncthreads();
    }
    if (t < BUCK_NODES && v < N_NODES) rowptr[v] = bktbase[b] + s[t] - d;
    if (b == 0 && t == 0) rowptr[N_NODES] = N_EDGES;
}

// ---------------- binB: per-bucket fine scatter to CSR (1024 threads) ----------------
// epack.x = (src << 15) | (combo*128)   [src: 17b, combo byte-offset: 15b]
// epack.y = dis[src] as float bits
__global__ __launch_bounds__(1024) void binB_kernel(
    const int2* __restrict__ gbin, const int* __restrict__ gcur,
    const int* __restrict__ rowptr, const float* __restrict__ dis,
    int2* __restrict__ epack) {
    __shared__ int curs[BUCK_NODES];
    int b = blockIdx.x, t = threadIdx.x;
    for (int i = t; i < BUCK_NODES; i += 1024) curs[i] = 0;
    __syncthreads();
    int n = gcur[b];
    const int2* mybin = gbin + (size_t)b * BIN_CAP;
    for (int i = t; i < n; i += 1024) {
        int2 q = mybin[i];
        int local = q.y - b * BUCK_NODES;
        int r = atomicAdd(&curs[local], 1);
        unsigned sx = (unsigned)q.x;
        int srci = (int)(sx & 0x1FFFF);
        int comboOff = (int)((sx >> 17) * 128u);   // <= 19456, fits 15 bits
        int2 rec;
        rec.x = (srci << 15) | comboOff;
        rec.y = __float_as_int(dis[srci]);
        epack[rowptr[q.y] + r] = rec;
    }
}

// ---------------- fused layer-1 aggregate + MFMA mm2 ----------------
// Block = 16 consecutive nodes; wave w owns nodes v0..v0+3 for aggregation.
// Edge prefetch: lanes 16n..16n+15 hold edges 0-15 (q1) and 16-31 (q2) of node n
// -> 2 coalesced vector loads cover the whole wave (deg<=32; rare serial tail).
// Edge consume: readlane broadcast (compile-time lane idx) + LDS TC gather.
// mm2: block-cooperative X(16x64,fp16) @ W2(64x64,fp16) via 2x mfma_f32_16x16x32_f16
// per wave (wave w -> output cols w*16..w*16+15); dv folded into A rows.
#define AGG_CHUNK(Q, LBASE, J0)                                                \
    _Pragma("unroll")                                                          \
    for (int i = 0; i < 8; ++i) {                                              \
        int off = __builtin_amdgcn_readlane((Q).x, (LBASE) + i) & 0x7FFF;      \
        int wb  = __builtin_amdgcn_readlane((Q).y, (LBASE) + i);               \
        off = ((J0) + i < cnt) ? off : 0;                                      \
        wb  = ((J0) + i < cnt) ? wb  : 0;                                      \
        __half tv = *(const __half*)((const char*)TCs + (off + lane2));        \
        acc = fmaf(__int_as_float(wb), __half2float(tv), acc);                 \
    }

#define AGG_NODE(N, RS, RE, DV, CO)                                            \
    {                                                                          \
        int deg = (RE) - (RS);                                                 \
        int cnt = deg > 32 ? 32 : deg;                                         \
        float acc = 0.0f;                                                      \
        AGG_CHUNK(q1, (N)*16, 0)                                               \
        if (cnt > 8)  { AGG_CHUNK(q1, (N)*16 + 8, 8) }                         \
        if (cnt > 16) { AGG_CHUNK(q2, (N)*16, 16) }                            \
        if (cnt > 24) { AGG_CHUNK(q2, (N)*16 + 8, 24) }                        \
        if (deg > 32) {                                                        \
            for (int e = (RS) + 32; e < (RE); ++e) {                           \
                int2 q = epack[e];                                             \
                __half tv = *(const __half*)((const char*)TCs +                \
                                             ((q.x & 0x7FFF) + lane2));        \
                acc = fmaf(__int_as_float(q.y), __half2float(tv), acc);        \
            }                                                                  \
        }                                                                      \
        __half hv = *(const __half*)((const char*)TCs + ((CO) + lane2));       \
        float val = (DV) * fmaf(__half2float(hv), (DV), acc) + bias;           \
        val = val > 0.0f ? val : 0.0f;                                         \
        xsA[w * 4 + (N)][lane] = __float2half_rn(val * (DV));                  \
    }

__global__ __launch_bounds__(256, 6) void agg1_mm2_kernel(
    const int2* __restrict__ epack, const int* __restrict__ rowptr,
    const int* __restrict__ combo, const float* __restrict__ dis,
    const __half* __restrict__ TCh, const float* __restrict__ W2,
    const float* __restrict__ b1, __half* __restrict__ h2s) {
    __shared__ __align__(16) __half TCs[NCOMBO * HID];  // 19,584 B
    __shared__ __align__(16) __half xsA[16][72];        //  2,304 B (stride 72: bank spread)
    __shared__ __align__(16) __half Dst[16 * 64];       //  2,048 B
    int t = threadIdx.x;
    int lane = t & 63, w = t >> 6;
    int lane2 = lane * 2;
    int vb = blockIdx.x * 16;
    int v0 = vb + w * 4;

    // per-lane sliced edge prefetch (longest latency chain - issue first)
    int sub = lane >> 4, sl = lane & 15;
    int rb = rowptr[v0 + sub];
    int2 q1 = epack[rb + sl];        // node sub, edges 0..15
    int2 q2 = epack[rb + 16 + sl];   // node sub, edges 16..31 (may over-read: ok, ws continues)

    // scalar row pointers
    int r0 = __builtin_amdgcn_readfirstlane(rowptr[v0]);
    int r1 = __builtin_amdgcn_readfirstlane(rowptr[v0 + 1]);
    int r2 = __builtin_amdgcn_readfirstlane(rowptr[v0 + 2]);
    int r3 = __builtin_amdgcn_readfirstlane(rowptr[v0 + 3]);
    int r4 = __builtin_amdgcn_readfirstlane(rowptr[v0 + 4]);

    // per-node epilogue scalars (issue early)
    float d0 = dis[v0], d1 = dis[v0 + 1], d2 = dis[v0 + 2], d3 = dis[v0 + 3];
    int o0 = combo[v0] << 7, o1 = combo[v0 + 1] << 7;
    int o2 = combo[v0 + 2] << 7, o3 = combo[v0 + 3] << 7;
    float bias = b1[lane];

    // B fragments of W2 for this wave's 16 output cols (built once, from global)
    f16x8 bf0, bf1;
    {
        int colw = (w << 4) + (lane & 15);
        int kb = (lane >> 4) * 8;
#pragma unroll
        for (int i = 0; i < 8; ++i) {
            bf0[i] = (_Float16)W2[(kb + i) * HID + colw];
            bf1[i] = (_Float16)W2[(32 + kb + i) * HID + colw];
        }
    }

    // stage TC table to LDS
    {
        const int4* s4 = (const int4*)TCh;
        int4* dd4 = (int4*)TCs;
        for (int i = t; i < NCOMBO * HID * 2 / 16; i += 256) dd4[i] = s4[i];
    }
    __syncthreads();   // also drains the edge prefetch

    AGG_NODE(0, r0, r1, d0, o0)
    AGG_NODE(1, r1, r2, d1, o1)
    AGG_NODE(2, r2, r3, d2, o2)
    AGG_NODE(3, r3, r4, d3, o3)

    __syncthreads();   // all 16 rows of xsA ready

    // A fragments: row = lane&15 (node), k = (lane>>4)*8 + i  (+32 for 2nd MFMA)
    const __half* xa = &xsA[lane & 15][0];
    f16x8 a0 = *(const f16x8*)(xa + (lane >> 4) * 8);
    f16x8 a1 = *(const f16x8*)(xa + 32 + (lane >> 4) * 8);
    f32x4 dacc = {0.0f, 0.0f, 0.0f, 0.0f};
    dacc = __builtin_amdgcn_mfma_f32_16x16x32_f16(a0, bf0, dacc, 0, 0, 0);
    dacc = __builtin_amdgcn_mfma_f32_16x16x32_f16(a1, bf1, dacc, 0, 0, 0);

    // D: col = lane&15 (within wave's 16-col block), row = (lane>>4)*4 + i (node)
    {
        int colg = (w << 4) + (lane & 15);
#pragma unroll
        for (int i = 0; i < 4; ++i)
            Dst[((lane >> 4) * 4 + i) * 64 + colg] = __float2half_rn(dacc[i]);
    }
    __syncthreads();

    // coalesced block store: 16 nodes x 64 feats fp16 = 2048 B contiguous
    {
        const uint2* ds2 = (const uint2*)Dst;
        uint2* go = (uint2*)(h2s + (size_t)vb * HID);
        go[t] = ds2[t];
    }
}

// ---------------- per-node edge accumulate for layer 2 ----------------
// sx: lane i holds epack[rs+i].x.  Broadcast h2s byte-offset per edge via readlane;
// gathers are per-lane vector loads (vmcnt, 8-deep in flight).
__device__ __forceinline__ float agg2_node(const int* __restrict__ epackx, int sx,
                                           int rs, int re, int lane, int lane2,
                                           const __half* __restrict__ h2s) {
    float acc = 0.0f;
    int p = rs;
    for (;;) {
        int avail = re - p;
        int cnt = avail > 64 ? 64 : avail;
        int vo = (int)((((unsigned)sx) >> 15) << 7);   // src*128, vectorized unpack
        int j = 0;
        for (; j + 8 <= cnt; j += 8) {
            float g[8];
#pragma unroll
            for (int i = 0; i < 8; ++i) {
                int off = __builtin_amdgcn_readlane(vo, j + i);
                g[i] = __half2float(*(const __half*)((const char*)h2s + (off + lane2)));
            }
#pragma unroll
            for (int i = 0; i < 8; ++i) acc += g[i];
        }
        if (j < cnt) {
#pragma unroll
            for (int i = 0; i < 8; ++i) {
                int jj = j + i;
                int off = __builtin_amdgcn_readlane(vo, jj & 63);
                float gv = __half2float(*(const __half*)((const char*)h2s + (off + lane2)));
                acc += (jj < cnt) ? gv : 0.0f;
            }
        }
        p += 64;
        if (p >= re) break;
        int idx = p + lane;
        idx = idx < N_EDGES ? idx : N_EDGES - 1;
        sx = epackx[idx * 2];
    }
    return acc;
}

// ---------------- layer-2 aggregate + pool: 4 nodes/wave, run-merged atomics ----------------
__global__ __launch_bounds__(256, 8) void agg2_pool_kernel(
    const int2* __restrict__ epack, const int* __restrict__ rowptr,
    const __half* __restrict__ h2s, const float* __restrict__ dis,
    const float* __restrict__ b2, const int* __restrict__ batch,
    float* __restrict__ pooled) {
    int t = threadIdx.x, lane = t & 63, w = t >> 6;
    int lane2 = lane * 2;
    const int* epackx = (const int*)epack;
    int v0 = (blockIdx.x * 4 + w) * 4;   // grid 6250

    int r0 = __builtin_amdgcn_readfirstlane(rowptr[v0]);
    int r1 = __builtin_amdgcn_readfirstlane(rowptr[v0 + 1]);
    int r2 = __builtin_amdgcn_readfirstlane(rowptr[v0 + 2]);
    int r3 = __builtin_amdgcn_readfirstlane(rowptr[v0 + 3]);
    int r4 = __builtin_amdgcn_readfirstlane(rowptr[v0 + 4]);

    int ia = r0 + lane; ia = ia < N_EDGES ? ia : N_EDGES - 1;
    int ib = r1 + lane; ib = ib < N_EDGES ? ib : N_EDGES - 1;
    int ic = r2 + lane; ic = ic < N_EDGES ? ic : N_EDGES - 1;
    int id = r3 + lane; id = id < N_EDGES ? id : N_EDGES - 1;
    int sa = epackx[ia * 2];
    int sb = epackx[ib * 2];
    int sc = epackx[ic * 2];
    int sd = epackx[id * 2];

    float bv = b2[lane];
    float acc0 = agg2_node(epackx, sa, r0, r1, lane, lane2, h2s);
    float acc1 = agg2_node(epackx, sb, r1, r2, lane, lane2, h2s);
    float acc2 = agg2_node(epackx, sc, r2, r3, lane, lane2, h2s);
    float acc3 = agg2_node(epackx, sd, r3, r4, lane, lane2, h2s);

#define AGG2_VAL(V, ACC, OUT)                                                  \
    {                                                                          \
        float dv = dis[V];                                                     \
        float self = __half2float(h2s[(size_t)(V) * HID + lane]);              \
        float val = dv * ((ACC) + self) + bv;                                  \
        OUT = val > 0.0f ? val : 0.0f;                                         \
    }
    float val0, val1, val2, val3;
    AGG2_VAL(v0, acc0, val0)
    AGG2_VAL(v0 + 1, acc1, val1)
    AGG2_VAL(v0 + 2, acc2, val2)
    AGG2_VAL(v0 + 3, acc3, val3)
#undef AGG2_VAL

    int g0 = __builtin_amdgcn_readfirstlane(batch[v0]);
    int g1 = __builtin_amdgcn_readfirstlane(batch[v0 + 1]);
    int g2 = __builtin_amdgcn_readfirstlane(batch[v0 + 2]);
    int g3 = __builtin_amdgcn_readfirstlane(batch[v0 + 3]);
    // batch is sorted: merge same-graph contributions into one atomic per run
    float s = val0; int g = g0;
    if (g1 == g) { s += val1; } else { unsafeAtomicAdd(&pooled[g * HID + lane], s); g = g1; s = val1; }
    if (g2 == g) { s += val2; } else { unsafeAtomicAdd(&pooled[g * HID + lane], s); g = g2; s = val2; }
    if (g3 == g) { s += val3; } else { unsafeAtomicAdd(&pooled[g * HID + lane], s); g = g3; s = val3; }
    unsafeAtomicAdd(&pooled[g * HID + lane], s);
}

// ---------------- logits ----------------
__global__ __launch_bounds__(64) void logits_kernel(
    const float* __restrict__ pooled, const int* __restrict__ cnt,
    const float* __restrict__ Wl, const float* __restrict__ bl,
    float* __restrict__ out) {
    __shared__ float row[HID];
    int g = blockIdx.x, t = threadIdx.x;
    int c = cnt[g]; if (c < 1) c = 1;
    row[t] = pooled[g * HID + t] / (float)c;
    __syncthreads();
    if (t < N_CLASSES) {
        float acc = bl[t];
#pragma unroll
        for (int k = 0; k < HID; ++k) acc = fmaf(row[k], Wl[k * N_CLASSES + t], acc);
        out[g * N_CLASSES + t] = acc;
    }
}

extern "C" void kernel_launch(void* const* d_in, const int* in_sizes, int n_in,
                              void* d_out, int out_size, void* d_ws, size_t ws_size,
                              hipStream_t stream) {
    const int*   shape_id = (const int*)d_in[0];
    const int*   color_id = (const int*)d_in[1];
    const int*   edge_idx = (const int*)d_in[2];
    const int*   batch    = (const int*)d_in[3];
    const float* st       = (const float*)d_in[4];
    const float* ct       = (const float*)d_in[5];
    const float* W1       = (const float*)d_in[6];
    const float* b1       = (const float*)d_in[7];
    const float* W2       = (const float*)d_in[8];
    const float* b2       = (const float*)d_in[9];
    const float* Wl       = (const float*)d_in[10];
    const float* bl       = (const float*)d_in[11];
    float* out = (float*)d_out;

    const int* src = edge_idx;
    const int* dst = edge_idx + N_EDGES;

    // workspace layout
    char* ws = (char*)d_ws;
    int*    combo   = (int*)   (ws + 0);            //   400,384 B
    float*  dis     = (float*) (ws + 400384);       //   400,384 B
    int*    bktbase = (int*)   (ws + 800768);       //     1,024 B
    int*    rowptr  = (int*)   (ws + 1201152);      //   400,384 B
    __half* TCh     = (__half*)(ws + 1603584);      //    19,968 B
    float*  pooled  = (float*) (ws + 1623552);      //   262,144 B
    int*    cnt     = (int*)   (ws + 1885696);      //     4,096 B
    int*    gcur    = (int*)   (ws + 1889792);      //     1,024 B
    int2*   epack   = (int2*)  (ws + 1890816);      // 12,800,000 B
    int2*   gbin    = (int2*)  (ws + 14690816);     // 14,680,064 B
    __half* h2s     = (__half*)(ws + 29370880);     // 12,800,000 B (total ~42.2 MB)

    hipMemsetAsync(pooled, 0, N_GRAPHS * HID * sizeof(float) + N_GRAPHS * sizeof(int), stream);
    hipMemsetAsync(gcur, 0, NBUCK * sizeof(int), stream);

    // 1. per-node combo + per-graph counts
    prep_kernel<<<SCAN_BLOCKS, 256, 0, stream>>>(shape_id, color_id, batch, combo, cnt);

    // 2. combined (shape,color)->h1 table (fp16)
    tc_kernel<<<NCOMBO, 64, 0, stream>>>(st, ct, W1, TCh);

    // 3. bin edges by dst-bucket
    binA_kernel<<<(N_EDGES + EPB - 1) / EPB, 512, 0, stream>>>(src, dst, combo, gcur, gbin);

    // 4. bucket bases from gcur
    bscan_kernel<<<1, 256, 0, stream>>>(gcur, bktbase);

    // 5. per-bucket degrees -> dis + rowptr
    bucket_kernel<<<NBUCK, 512, 0, stream>>>(gbin, gcur, bktbase, dis, rowptr);

    // 6. per-bucket scatter to CSR (1024 thr)
    binB_kernel<<<NBUCK, 1024, 0, stream>>>(gbin, gcur, rowptr, dis, epack);

    // 7. fused layer-1 aggregate + MFMA mm2 -> h2s (16 nodes/block)
    agg1_mm2_kernel<<<6250, 256, 0, stream>>>(epack, rowptr, combo, dis, TCh, W2, b1, h2s);

    // 8. layer-2 aggregate + pool (4 nodes/wave, run-merged atomics)
    agg2_pool_kernel<<<6250, 256, 0, stream>>>(epack, rowptr, h2s, dis, b2, batch, pooled);

    // 9. logits
    logits_kernel<<<N_GRAPHS, 64, 0, stream>>>(pooled, cnt, Wl, bl, out);
}

// Round 3
// 200.335 us; speedup vs baseline: 1.3729x; 1.2176x over previous
//
#include <hip/hip_runtime.h>
#include <hip/hip_bf16.h>
#include <hip/hip_fp16.h>

#define N_NODES   100000
#define N_EDGES   1600000
#define N_GRAPHS  1024
#define EMB       32
#define HID       64
#define N_CLASSES 10
#define SCAN_BLOCKS 391   // ceil(100000/256)
#define NCOMBO 153        // 17 shape ids x 9 color ids
#define BUCK_NODES 448    // nodes per dst-bucket
#define NBUCK 224         // ceil(100000/448)
#define BIN_CAP 8192      // per-bucket staging capacity (mean 7143, +12 sigma)
#define EPB 4096          // edges per binA block

typedef _Float16 f16x8 __attribute__((ext_vector_type(8)));
typedef float f32x4 __attribute__((ext_vector_type(4)));

// ---------------- prep: combo[v] + sorted-batch segment boundaries ----------------
// batch is sorted, so per-graph counts = gstart[g+1]-gstart[g].  Zero atomics:
// each g in [0,N_GRAPHS] gets gstart written exactly once by its boundary thread.
__global__ __launch_bounds__(256) void prep_kernel(
    const int* __restrict__ sid, const int* __restrict__ cid,
    const int* __restrict__ batch, int* __restrict__ combo, int* __restrict__ gstart) {
    int v = blockIdx.x * 256 + threadIdx.x;
    if (v < N_NODES) {
        combo[v] = sid[v] * 9 + cid[v];
        int b = batch[v];
        int bp = (v == 0) ? -1 : batch[v - 1];
        for (int g = bp + 1; g <= b; ++g) gstart[g] = v;      // boundary (usually 0 iters)
        if (v == N_NODES - 1) {
            for (int g = b + 1; g <= N_GRAPHS; ++g) gstart[g] = N_NODES;
        }
    }
}

// ---------------- combined table (fp16): TCh[s*9+c][j] = (st[s]@W1)[j] + (ct[c]@W1)[j] ----------------
__global__ __launch_bounds__(64) void tc_kernel(
    const float* __restrict__ st, const float* __restrict__ ct,
    const float* __restrict__ W1, __half* __restrict__ TCh) {
    int r = blockIdx.x, j = threadIdx.x;
    int s = r / 9, c = r % 9;
    float acc = 0.0f;
    if (s != 0) {
#pragma unroll
        for (int k = 0; k < EMB; ++k) acc = fmaf(st[s * EMB + k], W1[k * HID + j], acc);
    }
    if (c != 0) {
#pragma unroll
        for (int k = 0; k < EMB; ++k) acc = fmaf(ct[c * EMB + k], W1[k * HID + j], acc);
    }
    TCh[r * HID + j] = __float2half_rn(acc);
}

// ---------------- binA: block-local counting sort by dst-bucket, chunked flush ----------------
__global__ __launch_bounds__(512) void binA_kernel(
    const int* __restrict__ src, const int* __restrict__ dst,
    const int* __restrict__ combo, int* __restrict__ gcur,
    int2* __restrict__ gbin) {
    __shared__ int2 stg[EPB];            // 32 KB
    __shared__ int hist[NBUCK];
    __shared__ int base[NBUCK + 1];
    __shared__ int gstart[NBUCK];
    __shared__ int scanbuf[256];
    int t = threadIdx.x;
    int e0 = blockIdx.x * EPB;
    for (int i = t; i < NBUCK; i += 512) hist[i] = 0;
    __syncthreads();

    int2 myq[8];
    int mybo[8];
#pragma unroll
    for (int i = 0; i < 8; ++i) {
        int e = e0 + t + i * 512;
        if (e < N_EDGES) {
            int d = dst[e];
            int s = src[e];
            unsigned b = (unsigned)d / BUCK_NODES;
            int off = atomicAdd(&hist[b], 1);
            myq[i].x = s | (combo[s] << 17);
            myq[i].y = d;
            mybo[i] = (int)(b << 16) | off;
        } else {
            mybo[i] = -1;
        }
    }
    __syncthreads();

    int h = (t < NBUCK) ? hist[t] : 0;
    if (t < 256) scanbuf[t] = h;
    __syncthreads();
#pragma unroll
    for (int off = 1; off < 256; off <<= 1) {
        int x = (t < 256 && t >= off) ? scanbuf[t - off] : 0;
        __syncthreads();
        if (t < 256) scanbuf[t] += x;
        __syncthreads();
    }
    if (t < NBUCK) base[t] = scanbuf[t] - h;
    if (t == 0) base[NBUCK] = scanbuf[255];
    __syncthreads();
#pragma unroll
    for (int i = 0; i < 8; ++i) {
        if (mybo[i] >= 0) {
            int b = mybo[i] >> 16, off = mybo[i] & 0xFFFF;
            stg[base[b] + off] = myq[i];
        }
    }
    if (t < NBUCK) {
        int n = hist[t];
        gstart[t] = n ? atomicAdd(&gcur[t], n) : 0;
    }
    __syncthreads();
    int total = base[NBUCK];
    for (int i = t; i < total; i += 512) {
        int2 q = stg[i];
        unsigned b = (unsigned)q.y / BUCK_NODES;
        gbin[(size_t)b * BIN_CAP + gstart[b] + (i - base[b])] = q;
    }
}

// ---------------- bscan: exclusive scan of gcur[224] -> bktbase ----------------
__global__ __launch_bounds__(256) void bscan_kernel(const int* __restrict__ gcur,
                                                    int* __restrict__ bktbase) {
    __shared__ int s[256];
    int t = threadIdx.x;
    int g = (t < NBUCK) ? gcur[t] : 0;
    s[t] = g; __syncthreads();
#pragma unroll
    for (int off = 1; off < 256; off <<= 1) {
        int x = (t >= off) ? s[t - off] : 0;
        __syncthreads();
        s[t] += x;
        __syncthreads();
    }
    if (t < NBUCK) bktbase[t] = s[t] - g;
}

// ---------------- bucket: per-bucket degrees -> dis + rowptr ----------------
__global__ __launch_bounds__(512) void bucket_kernel(
    const int2* __restrict__ gbin, const int* __restrict__ gcur,
    const int* __restrict__ bktbase, float* __restrict__ dis,
    int* __restrict__ rowptr) {
    __shared__ int ldeg[BUCK_NODES];
    __shared__ int s[512];
    int b = blockIdx.x, t = threadIdx.x;
    for (int i = t; i < BUCK_NODES; i += 512) ldeg[i] = 0;
    __syncthreads();
    int n = gcur[b];
    const int2* mybin = gbin + (size_t)b * BIN_CAP;
    for (int i = t; i < n; i += 512)
        atomicAdd(&ldeg[mybin[i].y - b * BUCK_NODES], 1);
    __syncthreads();
    int d = (t < BUCK_NODES) ? ldeg[t] : 0;
    int v = b * BUCK_NODES + t;
    if (t < BUCK_NODES && v < N_NODES) dis[v] = rsqrtf(1.0f + (float)d);
    s[t] = d;
    __syncthreads();
#pragma unroll
    for (int off = 1; off < 512; off <<= 1) {
        int x = (t >= off) ? s[t - off] : 0;
        __syncthreads();
        s[t] += x;
        __syncthreads();
    }
    if (t < BUCK_NODES && v < N_NODES) rowptr[v] = bktbase[b] + s[t] - d;
    if (b == 0 && t == 0) rowptr[N_NODES] = N_EDGES;
}

// ---------------- binB: per-bucket fine scatter to CSR (1024 threads) ----------------
// epack.x = (src << 15) | (combo*128)   [src: 17b, combo byte-offset: 15b]
// epack.y = dis[src] as float bits
__global__ __launch_bounds__(1024) void binB_kernel(
    const int2* __restrict__ gbin, const int* __restrict__ gcur,
    const int* __restrict__ rowptr, const float* __restrict__ dis,
    int2* __restrict__ epack) {
    __shared__ int curs[BUCK_NODES];
    int b = blockIdx.x, t = threadIdx.x;
    for (int i = t; i < BUCK_NODES; i += 1024) curs[i] = 0;
    __syncthreads();
    int n = gcur[b];
    const int2* mybin = gbin + (size_t)b * BIN_CAP;
    for (int i = t; i < n; i += 1024) {
        int2 q = mybin[i];
        int local = q.y - b * BUCK_NODES;
        int r = atomicAdd(&curs[local], 1);
        unsigned sx = (unsigned)q.x;
        int srci = (int)(sx & 0x1FFFF);
        int comboOff = (int)((sx >> 17) * 128u);   // <= 19456, fits 15 bits
        int2 rec;
        rec.x = (srci << 15) | comboOff;
        rec.y = __float_as_int(dis[srci]);
        epack[rowptr[q.y] + r] = rec;
    }
}

// ---------------- fused layer-1 aggregate + MFMA mm2 ----------------
// Block = 16 consecutive nodes; wave w owns nodes v0..v0+3 for aggregation.
// Edge prefetch: lanes 16n..16n+15 hold edges 0-15 (q1) and 16-31 (q2) of node n
// -> 2 coalesced vector loads cover the whole wave (deg<=32; rare serial tail).
// Edge consume: readlane broadcast (compile-time lane idx) + LDS TC gather.
// mm2: block-cooperative X(16x64,fp16) @ W2(64x64,fp16) via 2x mfma_f32_16x16x32_f16
// per wave (wave w -> output cols w*16..w*16+15); dv folded into A rows.
#define AGG_CHUNK(Q, LBASE, J0)                                                \
    _Pragma("unroll")                                                          \
    for (int i = 0; i < 8; ++i) {                                              \
        int off = __builtin_amdgcn_readlane((Q).x, (LBASE) + i) & 0x7FFF;      \
        int wb  = __builtin_amdgcn_readlane((Q).y, (LBASE) + i);               \
        off = ((J0) + i < cnt) ? off : 0;                                      \
        wb  = ((J0) + i < cnt) ? wb  : 0;                                      \
        __half tv = *(const __half*)((const char*)TCs + (off + lane2));        \
        acc = fmaf(__int_as_float(wb), __half2float(tv), acc);                 \
    }

#define AGG_NODE(N, RS, RE, DV, CO)                                            \
    {                                                                          \
        int deg = (RE) - (RS);                                                 \
        int cnt = deg > 32 ? 32 : deg;                                         \
        float acc = 0.0f;                                                      \
        AGG_CHUNK(q1, (N)*16, 0)                                               \
        if (cnt > 8)  { AGG_CHUNK(q1, (N)*16 + 8, 8) }                         \
        if (cnt > 16) { AGG_CHUNK(q2, (N)*16, 16) }                            \
        if (cnt > 24) { AGG_CHUNK(q2, (N)*16 + 8, 24) }                        \
        if (deg > 32) {                                                        \
            for (int e = (RS) + 32; e < (RE); ++e) {                           \
                int2 q = epack[e];                                             \
                __half tv = *(const __half*)((const char*)TCs +                \
                                             ((q.x & 0x7FFF) + lane2));        \
                acc = fmaf(__int_as_float(q.y), __half2float(tv), acc);        \
            }                                                                  \
        }                                                                      \
        __half hv = *(const __half*)((const char*)TCs + ((CO) + lane2));       \
        float val = (DV) * fmaf(__half2float(hv), (DV), acc) + bias;           \
        val = val > 0.0f ? val : 0.0f;                                         \
        xsA[w * 4 + (N)][lane] = __float2half_rn(val * (DV));                  \
    }

__global__ __launch_bounds__(256, 6) void agg1_mm2_kernel(
    const int2* __restrict__ epack, const int* __restrict__ rowptr,
    const int* __restrict__ combo, const float* __restrict__ dis,
    const __half* __restrict__ TCh, const float* __restrict__ W2,
    const float* __restrict__ b1, __half* __restrict__ h2s) {
    __shared__ __align__(16) __half TCs[NCOMBO * HID];  // 19,584 B
    __shared__ __align__(16) __half xsA[16][72];        //  2,304 B (stride 72: bank spread)
    __shared__ __align__(16) __half Dst[16 * 64];       //  2,048 B
    int t = threadIdx.x;
    int lane = t & 63, w = t >> 6;
    int lane2 = lane * 2;
    int vb = blockIdx.x * 16;
    int v0 = vb + w * 4;

    // per-lane sliced edge prefetch (longest latency chain - issue first)
    int sub = lane >> 4, sl = lane & 15;
    int rb = rowptr[v0 + sub];
    int2 q1 = epack[rb + sl];        // node sub, edges 0..15
    int2 q2 = epack[rb + 16 + sl];   // node sub, edges 16..31 (may over-read: ok, ws continues)

    // scalar row pointers
    int r0 = __builtin_amdgcn_readfirstlane(rowptr[v0]);
    int r1 = __builtin_amdgcn_readfirstlane(rowptr[v0 + 1]);
    int r2 = __builtin_amdgcn_readfirstlane(rowptr[v0 + 2]);
    int r3 = __builtin_amdgcn_readfirstlane(rowptr[v0 + 3]);
    int r4 = __builtin_amdgcn_readfirstlane(rowptr[v0 + 4]);

    // per-node epilogue scalars (issue early)
    float d0 = dis[v0], d1 = dis[v0 + 1], d2 = dis[v0 + 2], d3 = dis[v0 + 3];
    int o0 = combo[v0] << 7, o1 = combo[v0 + 1] << 7;
    int o2 = combo[v0 + 2] << 7, o3 = combo[v0 + 3] << 7;
    float bias = b1[lane];

    // B fragments of W2 for this wave's 16 output cols (built once, from global)
    f16x8 bf0, bf1;
    {
        int colw = (w << 4) + (lane & 15);
        int kb = (lane >> 4) * 8;
#pragma unroll
        for (int i = 0; i < 8; ++i) {
            bf0[i] = (_Float16)W2[(kb + i) * HID + colw];
            bf1[i] = (_Float16)W2[(32 + kb + i) * HID + colw];
        }
    }

    // stage TC table to LDS
    {
        const int4* s4 = (const int4*)TCh;
        int4* dd4 = (int4*)TCs;
        for (int i = t; i < NCOMBO * HID * 2 / 16; i += 256) dd4[i] = s4[i];
    }
    __syncthreads();   // also drains the edge prefetch

    AGG_NODE(0, r0, r1, d0, o0)
    AGG_NODE(1, r1, r2, d1, o1)
    AGG_NODE(2, r2, r3, d2, o2)
    AGG_NODE(3, r3, r4, d3, o3)

    __syncthreads();   // all 16 rows of xsA ready

    // A fragments: row = lane&15 (node), k = (lane>>4)*8 + i  (+32 for 2nd MFMA)
    const __half* xa = &xsA[lane & 15][0];
    f16x8 a0 = *(const f16x8*)(xa + (lane >> 4) * 8);
    f16x8 a1 = *(const f16x8*)(xa + 32 + (lane >> 4) * 8);
    f32x4 dacc = {0.0f, 0.0f, 0.0f, 0.0f};
    dacc = __builtin_amdgcn_mfma_f32_16x16x32_f16(a0, bf0, dacc, 0, 0, 0);
    dacc = __builtin_amdgcn_mfma_f32_16x16x32_f16(a1, bf1, dacc, 0, 0, 0);

    // D: col = lane&15 (within wave's 16-col block), row = (lane>>4)*4 + i (node)
    {
        int colg = (w << 4) + (lane & 15);
#pragma unroll
        for (int i = 0; i < 4; ++i)
            Dst[((lane >> 4) * 4 + i) * 64 + colg] = __float2half_rn(dacc[i]);
    }
    __syncthreads();

    // coalesced block store: 16 nodes x 64 feats fp16 = 2048 B contiguous
    {
        const uint2* ds2 = (const uint2*)Dst;
        uint2* go = (uint2*)(h2s + (size_t)vb * HID);
        go[t] = ds2[t];
    }
}

// ---------------- per-node edge accumulate for layer 2 ----------------
// sx: lane i holds epack[rs+i].x.  Broadcast h2s byte-offset per edge via readlane;
// gathers are per-lane vector loads (vmcnt, 8-deep in flight).
__device__ __forceinline__ float agg2_node(const int* __restrict__ epackx, int sx,
                                           int rs, int re, int lane, int lane2,
                                           const __half* __restrict__ h2s) {
    float acc = 0.0f;
    int p = rs;
    for (;;) {
        int avail = re - p;
        int cnt = avail > 64 ? 64 : avail;
        int vo = (int)((((unsigned)sx) >> 15) << 7);   // src*128, vectorized unpack
        int j = 0;
        for (; j + 8 <= cnt; j += 8) {
            float g[8];
#pragma unroll
            for (int i = 0; i < 8; ++i) {
                int off = __builtin_amdgcn_readlane(vo, j + i);
                g[i] = __half2float(*(const __half*)((const char*)h2s + (off + lane2)));
            }
#pragma unroll
            for (int i = 0; i < 8; ++i) acc += g[i];
        }
        if (j < cnt) {
#pragma unroll
            for (int i = 0; i < 8; ++i) {
                int jj = j + i;
                int off = __builtin_amdgcn_readlane(vo, jj & 63);
                float gv = __half2float(*(const __half*)((const char*)h2s + (off + lane2)));
                acc += (jj < cnt) ? gv : 0.0f;
            }
        }
        p += 64;
        if (p >= re) break;
        int idx = p + lane;
        idx = idx < N_EDGES ? idx : N_EDGES - 1;
        sx = epackx[idx * 2];
    }
    return acc;
}

// ---------------- layer-2 aggregate + pool: 4 nodes/wave, run-merged atomics ----------------
__global__ __launch_bounds__(256, 8) void agg2_pool_kernel(
    const int2* __restrict__ epack, const int* __restrict__ rowptr,
    const __half* __restrict__ h2s, const float* __restrict__ dis,
    const float* __restrict__ b2, const int* __restrict__ batch,
    float* __restrict__ pooled) {
    int t = threadIdx.x, lane = t & 63, w = t >> 6;
    int lane2 = lane * 2;
    const int* epackx = (const int*)epack;
    int v0 = (blockIdx.x * 4 + w) * 4;   // grid 6250

    int r0 = __builtin_amdgcn_readfirstlane(rowptr[v0]);
    int r1 = __builtin_amdgcn_readfirstlane(rowptr[v0 + 1]);
    int r2 = __builtin_amdgcn_readfirstlane(rowptr[v0 + 2]);
    int r3 = __builtin_amdgcn_readfirstlane(rowptr[v0 + 3]);
    int r4 = __builtin_amdgcn_readfirstlane(rowptr[v0 + 4]);

    int ia = r0 + lane; ia = ia < N_EDGES ? ia : N_EDGES - 1;
    int ib = r1 + lane; ib = ib < N_EDGES ? ib : N_EDGES - 1;
    int ic = r2 + lane; ic = ic < N_EDGES ? ic : N_EDGES - 1;
    int id = r3 + lane; id = id < N_EDGES ? id : N_EDGES - 1;
    int sa = epackx[ia * 2];
    int sb = epackx[ib * 2];
    int sc = epackx[ic * 2];
    int sd = epackx[id * 2];

    float bv = b2[lane];
    float acc0 = agg2_node(epackx, sa, r0, r1, lane, lane2, h2s);
    float acc1 = agg2_node(epackx, sb, r1, r2, lane, lane2, h2s);
    float acc2 = agg2_node(epackx, sc, r2, r3, lane, lane2, h2s);
    float acc3 = agg2_node(epackx, sd, r3, r4, lane, lane2, h2s);

#define AGG2_VAL(V, ACC, OUT)                                                  \
    {                                                                          \
        float dv = dis[V];                                                     \
        float self = __half2float(h2s[(size_t)(V) * HID + lane]);              \
        float val = dv * ((ACC) + self) + bv;                                  \
        OUT = val > 0.0f ? val : 0.0f;                                         \
    }
    float val0, val1, val2, val3;
    AGG2_VAL(v0, acc0, val0)
    AGG2_VAL(v0 + 1, acc1, val1)
    AGG2_VAL(v0 + 2, acc2, val2)
    AGG2_VAL(v0 + 3, acc3, val3)
#undef AGG2_VAL

    int g0 = __builtin_amdgcn_readfirstlane(batch[v0]);
    int g1 = __builtin_amdgcn_readfirstlane(batch[v0 + 1]);
    int g2 = __builtin_amdgcn_readfirstlane(batch[v0 + 2]);
    int g3 = __builtin_amdgcn_readfirstlane(batch[v0 + 3]);
    // batch is sorted: merge same-graph contributions into one atomic per run
    float s = val0; int g = g0;
    if (g1 == g) { s += val1; } else { unsafeAtomicAdd(&pooled[g * HID + lane], s); g = g1; s = val1; }
    if (g2 == g) { s += val2; } else { unsafeAtomicAdd(&pooled[g * HID + lane], s); g = g2; s = val2; }
    if (g3 == g) { s += val3; } else { unsafeAtomicAdd(&pooled[g * HID + lane], s); g = g3; s = val3; }
    unsafeAtomicAdd(&pooled[g * HID + lane], s);
}

// ---------------- logits ----------------
__global__ __launch_bounds__(64) void logits_kernel(
    const float* __restrict__ pooled, const int* __restrict__ gstart,
    const float* __restrict__ Wl, const float* __restrict__ bl,
    float* __restrict__ out) {
    __shared__ float row[HID];
    int g = blockIdx.x, t = threadIdx.x;
    int c = gstart[g + 1] - gstart[g]; if (c < 1) c = 1;
    row[t] = pooled[g * HID + t] / (float)c;
    __syncthreads();
    if (t < N_CLASSES) {
        float acc = bl[t];
#pragma unroll
        for (int k = 0; k < HID; ++k) acc = fmaf(row[k], Wl[k * N_CLASSES + t], acc);
        out[g * N_CLASSES + t] = acc;
    }
}

extern "C" void kernel_launch(void* const* d_in, const int* in_sizes, int n_in,
                              void* d_out, int out_size, void* d_ws, size_t ws_size,
                              hipStream_t stream) {
    const int*   shape_id = (const int*)d_in[0];
    const int*   color_id = (const int*)d_in[1];
    const int*   edge_idx = (const int*)d_in[2];
    const int*   batch    = (const int*)d_in[3];
    const float* st       = (const float*)d_in[4];
    const float* ct       = (const float*)d_in[5];
    const float* W1       = (const float*)d_in[6];
    const float* b1       = (const float*)d_in[7];
    const float* W2       = (const float*)d_in[8];
    const float* b2       = (const float*)d_in[9];
    const float* Wl       = (const float*)d_in[10];
    const float* bl       = (const float*)d_in[11];
    float* out = (float*)d_out;

    const int* src = edge_idx;
    const int* dst = edge_idx + N_EDGES;

    // workspace layout
    char* ws = (char*)d_ws;
    int*    combo   = (int*)   (ws + 0);            //   400,384 B
    float*  dis     = (float*) (ws + 400384);       //   400,384 B
    int*    bktbase = (int*)   (ws + 800768);       //     1,024 B
    int*    gstart  = (int*)   (ws + 801792);       //     4,112 B (in former gap)
    int*    rowptr  = (int*)   (ws + 1201152);      //   400,384 B
    __half* TCh     = (__half*)(ws + 1603584);      //    19,968 B
    float*  pooled  = (float*) (ws + 1623552);      //   262,144 B
    int*    gcur    = (int*)   (ws + 1889792);      //     1,024 B
    int2*   epack   = (int2*)  (ws + 1890816);      // 12,800,000 B
    int2*   gbin    = (int2*)  (ws + 14690816);     // 14,680,064 B
    __half* h2s     = (__half*)(ws + 29370880);     // 12,800,000 B (total ~42.2 MB)

    hipMemsetAsync(pooled, 0, N_GRAPHS * HID * sizeof(float), stream);
    hipMemsetAsync(gcur, 0, NBUCK * sizeof(int), stream);

    // 1. per-node combo + sorted-batch boundaries (no atomics)
    prep_kernel<<<SCAN_BLOCKS, 256, 0, stream>>>(shape_id, color_id, batch, combo, gstart);

    // 2. combined (shape,color)->h1 table (fp16)
    tc_kernel<<<NCOMBO, 64, 0, stream>>>(st, ct, W1, TCh);

    // 3. bin edges by dst-bucket
    binA_kernel<<<(N_EDGES + EPB - 1) / EPB, 512, 0, stream>>>(src, dst, combo, gcur, gbin);

    // 4. bucket bases from gcur
    bscan_kernel<<<1, 256, 0, stream>>>(gcur, bktbase);

    // 5. per-bucket degrees -> dis + rowptr
    bucket_kernel<<<NBUCK, 512, 0, stream>>>(gbin, gcur, bktbase, dis, rowptr);

    // 6. per-bucket scatter to CSR (1024 thr)
    binB_kernel<<<NBUCK, 1024, 0, stream>>>(gbin, gcur, rowptr, dis, epack);

    // 7. fused layer-1 aggregate + MFMA mm2 -> h2s (16 nodes/block)
    agg1_mm2_kernel<<<6250, 256, 0, stream>>>(epack, rowptr, combo, dis, TCh, W2, b1, h2s);

    // 8. layer-2 aggregate + pool (4 nodes/wave, run-merged atomics)
    agg2_pool_kernel<<<6250, 256, 0, stream>>>(epack, rowptr, h2s, dis, b2, batch, pooled);

    // 9. logits (counts from gstart boundaries)
    logits_kernel<<<N_GRAPHS, 64, 0, stream>>>(pooled, gstart, Wl, bl, out);
}